// Round 3
// baseline (163.934 us; speedup 1.0000x reference)
//
#include <hip/hip_runtime.h>
#include <stdint.h>

#define N_NODES   4096
#define N_EDGES   128
#define D_X       128
#define PE_DIM    64
#define NUM_WALKS 10
#define WALK_LEN  5
#define N_WALKS_TOT (N_NODES * NUM_WALKS)   /* 40960 */
#define OUT_COLS  (D_X + PE_DIM)            /* 192 */
#define OUT_TOT   (N_NODES * OUT_COLS)      /* 786432 */
#define ROW_CAP   512u                      /* adjacency row stride (u16); deg ~205, max ~270 */

/* workspace layout (bytes) */
#define OFF_MASKS   0u                                   /* 4096*16 = 65536 */
#define OFF_DEG     (OFF_MASKS + N_NODES * 16u)          /* 16384 */
#define OFF_ADJ     (OFF_DEG + N_NODES * 4u)             /* 81920: 1KB aligned; 4 MiB */
#define OFF_PE      (OFF_ADJ + N_NODES * ROW_CAP * 2u)   /* 4276224; 1 MiB */
#define OFF_CNT     (OFF_PE + N_NODES * PE_DIM * 4u)     /* 16 KiB */

/* ---- JAX threefry2x32 (20 rounds) — matches np reference bit-exactly ---- */
__device__ __forceinline__ void tf2x32(uint32_t kk0, uint32_t kk1,
                                       uint32_t x0, uint32_t x1,
                                       uint32_t& o0, uint32_t& o1) {
  const uint32_t kk2 = kk0 ^ kk1 ^ 0x1BD11BDAu;
  x0 += kk0; x1 += kk1;
  auto rnd = [&](int r) {
    x0 += x1;
    x1 = (x1 << r) | (x1 >> (32 - r));
    x1 ^= x0;
  };
  rnd(13); rnd(15); rnd(26); rnd(6);   x0 += kk1; x1 += kk2 + 1u;
  rnd(17); rnd(29); rnd(16); rnd(24);  x0 += kk2; x1 += kk0 + 2u;
  rnd(13); rnd(15); rnd(26); rnd(6);   x0 += kk0; x1 += kk1 + 3u;
  rnd(17); rnd(29); rnd(16); rnd(24);  x0 += kk1; x1 += kk2 + 4u;
  rnd(13); rnd(15); rnd(26); rnd(6);   x0 += kk2; x1 += kk0 + 5u;
  o0 = x0; o1 = x1;
}

/* ---- K1: 128-bit incidence masks (one wave per node) ---- */
__global__ void k_masks(const float* __restrict__ inc,
                        ulonglong2* __restrict__ masks) {
  const int wid = threadIdx.x >> 6, lane = threadIdx.x & 63;
  const int i = blockIdx.x * 4 + wid;
  const float a = inc[i * N_EDGES + lane];
  const float b = inc[i * N_EDGES + 64 + lane];
  const unsigned long long m0 = __ballot(a != 0.f);
  const unsigned long long m1 = __ballot(b != 0.f);
  if (lane == 0) masks[i] = make_ulonglong2(m0, m1);
}

/* ---- K2: adjacency rows (fixed stride) + degree, masks staged in LDS ---- */
__global__ void __launch_bounds__(512)
k_adj(const ulonglong2* __restrict__ masks,
      unsigned short* __restrict__ adj, unsigned int* __restrict__ deg) {
  __shared__ ulonglong2 sm[N_NODES];
  for (int k = threadIdx.x; k < N_NODES; k += 512) sm[k] = masks[k];
  __syncthreads();
  const int wid = threadIdx.x >> 6, lane = threadIdx.x & 63;
  const int i = blockIdx.x * 8 + wid;
  const ulonglong2 mi = sm[i];
  unsigned short* row = adj + (unsigned int)i * ROW_CAP;
  unsigned int base = 0;
  for (int g = 0; g < N_NODES / 64; ++g) {
    const int j = g * 64 + lane;
    const ulonglong2 mj = sm[j];
    const bool pred = (((mi.x & mj.x) | (mi.y & mj.y)) != 0ull) && (j != i);
    const unsigned long long bal = __ballot(pred);
    if (pred) {
      const unsigned int off =
          (unsigned int)__popcll(bal & ((1ull << lane) - 1ull));
      const unsigned int pos = base + off;
      if (pos < ROW_CAP) row[pos] = (unsigned short)j;
    }
    base += (unsigned int)__popcll(bal);
  }
  if (lane == 0) deg[i] = (base < ROW_CAP) ? base : ROW_CAP;
}

/* ---- K3: walks + mean embedding + scatter (one wave per walk) ---- */
__global__ void __launch_bounds__(256)
k_walk(const unsigned int* __restrict__ deg,
       const unsigned short* __restrict__ adj,
       const float* __restrict__ embed,
       float* __restrict__ pe_sum, unsigned int* __restrict__ cnt) {
  const int wid = threadIdx.x >> 6, lane = threadIdx.x & 63;
  const int w = blockIdx.x * 4 + wid;

  /* step keys: fold-like split of base key (0,42); constant-folds at -O3 */
  uint32_t k0[4], k1[4];
#pragma unroll
  for (int t = 0; t < 4; ++t) tf2x32(0u, 42u, 0u, (uint32_t)t, k0[t], k1[t]);

  uint32_t nodes[WALK_LEN];
  nodes[0] = (uint32_t)(w / NUM_WALKS);
  uint32_t validbits = 1u;
  bool alive = true;
  uint32_t cur = nodes[0];
  const uint32_t wbase = (uint32_t)w * (uint32_t)N_NODES;

#pragma unroll
  for (int t = 0; t < WALK_LEN - 1; ++t) {
    const unsigned int degc = deg[cur];
    alive = alive && (degc > 0);
    if (alive) {
      const uint32_t* row32 =
          (const uint32_t*)(adj + ((unsigned int)cur << 9));
      unsigned long long best = 0ull;
      for (unsigned int s0 = 0; s0 < degc; s0 += 256) {
        const unsigned int s = s0 + (unsigned int)lane * 4u;
        const uint2 pk = *(const uint2*)(row32 + (s >> 1));
        const uint32_t nn[4] = {pk.x & 0xFFFFu, pk.x >> 16,
                                pk.y & 0xFFFFu, pk.y >> 16};
#pragma unroll
        for (int q = 0; q < 4; ++q) {
          const uint32_t n = nn[q];
          uint32_t o0, o1;
          tf2x32(k0[t], k1[t], 0u, wbase + n, o0, o1);
          const uint32_t val = (o0 ^ o1) >> 9; /* monotone proxy for gumbel */
          unsigned long long cand =
              (unsigned long long)val * 4096ull +
              (unsigned long long)(uint32_t)(4095u - n);
          cand = (s + (unsigned int)q < degc) ? cand : 0ull;
          if (cand > best) best = cand;
        }
      }
#pragma unroll
      for (int d = 32; d >= 1; d >>= 1) {
        const unsigned long long o = __shfl_xor(best, d);
        if (o > best) best = o;
      }
      cur = 4095u - (uint32_t)(best & 4095ull);
      validbits |= (1u << (t + 1));
    }
    nodes[t + 1] = cur;
  }

  /* mean embedding over valid positions; lane == dim (PE_DIM == 64) */
  const int len = __popc(validbits);
  float s = 0.f;
#pragma unroll
  for (int p = 0; p < WALK_LEN; ++p)
    if (validbits & (1u << p)) s += embed[nodes[p] * PE_DIM + lane];
  const float m = s / (float)len;

#pragma unroll
  for (int p = 0; p < WALK_LEN; ++p)
    if (validbits & (1u << p)) {
      atomicAdd(&pe_sum[nodes[p] * PE_DIM + lane], m);
      if (lane == 0) atomicAdd(&cnt[nodes[p]], 1u);
    }
}

/* ---- K4: out = [x | pe_sum/cnt] in f32 ---- */
__global__ void k_out(const float* __restrict__ x,
                      const float* __restrict__ pe_sum,
                      const unsigned int* __restrict__ cnt,
                      float* __restrict__ out) {
  const int idx = blockIdx.x * 256 + threadIdx.x;
  const int i = idx / OUT_COLS;
  const int c = idx - i * OUT_COLS;
  if (c < D_X) {
    out[idx] = x[i * D_X + c];
  } else {
    const int d = c - D_X;
    const unsigned int k = cnt[i];
    out[idx] = (k > 0) ? pe_sum[i * PE_DIM + d] / (float)k : 0.f;
  }
}

extern "C" void kernel_launch(void* const* d_in, const int* in_sizes, int n_in,
                              void* d_out, int out_size, void* d_ws, size_t ws_size,
                              hipStream_t stream) {
  const float* x   = (const float*)d_in[0];
  const float* inc = (const float*)d_in[1];
  const float* emb = (const float*)d_in[2];

  char* ws = (char*)d_ws;
  ulonglong2*     masks = (ulonglong2*)(ws + OFF_MASKS);
  unsigned int*   deg   = (unsigned int*)(ws + OFF_DEG);
  unsigned short* adj   = (unsigned short*)(ws + OFF_ADJ);
  float*          pe    = (float*)(ws + OFF_PE);
  unsigned int*   cnt   = (unsigned int*)(ws + OFF_CNT);

  /* pe_sum + cnt are contiguous: zero both each call (graph-capture safe) */
  hipMemsetAsync(pe, 0, (size_t)N_NODES * PE_DIM * 4u + (size_t)N_NODES * 4u,
                 stream);

  k_masks<<<N_NODES / 4, 256, 0, stream>>>(inc, masks);
  k_adj  <<<N_NODES / 8, 512, 0, stream>>>(masks, adj, deg);
  k_walk <<<N_WALKS_TOT / 4, 256, 0, stream>>>(deg, adj, emb, pe, cnt);
  k_out  <<<OUT_TOT / 256, 256, 0, stream>>>(x, pe, cnt, (float*)d_out);
}

// Round 4
// 93.867 us; speedup vs baseline: 1.7464x; 1.7464x over previous
//
#include <hip/hip_runtime.h>
#include <stdint.h>

#define N_NODES   4096
#define N_EDGES   128
#define D_X       128
#define PE_DIM    64
#define NUM_WALKS 10
#define WALK_LEN  5
#define N_WALKS_TOT (N_NODES * NUM_WALKS)   /* 40960 */
#define OUT_COLS  (D_X + PE_DIM)            /* 192 */
#define OUT_TOT   (N_NODES * OUT_COLS)      /* 786432 */
#define ROW_CAP   512u                      /* adjacency row stride (u16) */

/* workspace layout (bytes) — total ~5.3 MiB (proven size) */
#define OFF_MASKS   0u                                   /* 4096*16 = 65536 */
#define OFF_DEG     (OFF_MASKS + N_NODES * 16u)          /* 16384 */
#define OFF_ADJ     (OFF_DEG + N_NODES * 4u)             /* 4 MiB */
#define OFF_PE      (OFF_ADJ + N_NODES * ROW_CAP * 2u)   /* 1 MiB */
#define OFF_CNT     (OFF_PE + N_NODES * PE_DIM * 4u)     /* 16 KiB */

/* ---- threefry2x32 (20 rounds) — used as a cheap high-quality PRF ---- */
__device__ __forceinline__ void tf2x32(uint32_t kk0, uint32_t kk1,
                                       uint32_t x0, uint32_t x1,
                                       uint32_t& o0, uint32_t& o1) {
  const uint32_t kk2 = kk0 ^ kk1 ^ 0x1BD11BDAu;
  x0 += kk0; x1 += kk1;
  auto rnd = [&](int r) {
    x0 += x1;
    x1 = (x1 << r) | (x1 >> (32 - r));
    x1 ^= x0;
  };
  rnd(13); rnd(15); rnd(26); rnd(6);   x0 += kk1; x1 += kk2 + 1u;
  rnd(17); rnd(29); rnd(16); rnd(24);  x0 += kk2; x1 += kk0 + 2u;
  rnd(13); rnd(15); rnd(26); rnd(6);   x0 += kk0; x1 += kk1 + 3u;
  rnd(17); rnd(29); rnd(16); rnd(24);  x0 += kk1; x1 += kk2 + 4u;
  rnd(13); rnd(15); rnd(26); rnd(6);   x0 += kk2; x1 += kk0 + 5u;
  o0 = x0; o1 = x1;
}

/* ---- K1: 128-bit incidence masks (one wave per node) ---- */
__global__ void k_masks(const float* __restrict__ inc,
                        ulonglong2* __restrict__ masks) {
  const int wid = threadIdx.x >> 6, lane = threadIdx.x & 63;
  const int i = blockIdx.x * 4 + wid;
  const float a = inc[i * N_EDGES + lane];
  const float b = inc[i * N_EDGES + 64 + lane];
  const unsigned long long m0 = __ballot(a != 0.f);
  const unsigned long long m1 = __ballot(b != 0.f);
  if (lane == 0) masks[i] = make_ulonglong2(m0, m1);
}

/* ---- K2: adjacency rows (fixed stride) + degree, masks staged in LDS ---- */
__global__ void __launch_bounds__(512)
k_adj(const ulonglong2* __restrict__ masks,
      unsigned short* __restrict__ adj, unsigned int* __restrict__ deg) {
  __shared__ ulonglong2 sm[N_NODES];
  for (int k = threadIdx.x; k < N_NODES; k += 512) sm[k] = masks[k];
  __syncthreads();
  const int wid = threadIdx.x >> 6, lane = threadIdx.x & 63;
  const int i = blockIdx.x * 8 + wid;
  const ulonglong2 mi = sm[i];
  unsigned short* row = adj + (unsigned int)i * ROW_CAP;
  unsigned int base = 0;
  for (int g = 0; g < N_NODES / 64; ++g) {
    const int j = g * 64 + lane;
    const ulonglong2 mj = sm[j];
    const bool pred = (((mi.x & mj.x) | (mi.y & mj.y)) != 0ull) && (j != i);
    const unsigned long long bal = __ballot(pred);
    if (pred) {
      const unsigned int off =
          (unsigned int)__popcll(bal & ((1ull << lane) - 1ull));
      const unsigned int pos = base + off;
      if (pos < ROW_CAP) row[pos] = (unsigned short)j;
    }
    base += (unsigned int)__popcll(bal);
  }
  if (lane == 0) deg[i] = (base < ROW_CAP) ? base : ROW_CAP;
}

/* ---- K3: walks (1 uniform draw per step) + mean embed + scatter ----
   Graph is symmetric => once a walk leaves its start it never hits a
   dead end: every walk is either full-length (deg(start)>0) or length-1. */
__global__ void __launch_bounds__(256)
k_walk(const unsigned int* __restrict__ deg,
       const unsigned short* __restrict__ adj,
       const float* __restrict__ embed,
       float* __restrict__ pe_sum, unsigned int* __restrict__ cnt) {
  const int wid = threadIdx.x >> 6, lane = threadIdx.x & 63;
  const int w = blockIdx.x * 4 + wid;

  /* 4 independent u32 per walk from 2 threefry blocks (lanes 0/1) */
  uint32_t a0, a1;
  tf2x32(0u, 42u, (uint32_t)w, (uint32_t)(lane & 1), a0, a1);
  const uint32_t rnd0 = __shfl(a0, 0);
  const uint32_t rnd1 = __shfl(a1, 0);
  const uint32_t rnd2 = __shfl(a0, 1);
  const uint32_t rnd3 = __shfl(a1, 1);

  const uint32_t n0 = (uint32_t)w / NUM_WALKS;
  uint32_t n1, n2, n3, n4, nvalid;
  const unsigned int d0 = deg[n0];
  if (d0 == 0) {
    n1 = n2 = n3 = n4 = n0;
    nvalid = 1u;
  } else {
    uint32_t cur = n0;
    unsigned int d;
    cur = adj[(cur << 9) + (uint32_t)(((uint64_t)rnd0 * d0) >> 32)]; n1 = cur;
    d = deg[cur];
    cur = adj[(cur << 9) + (uint32_t)(((uint64_t)rnd1 * d) >> 32)]; n2 = cur;
    d = deg[cur];
    cur = adj[(cur << 9) + (uint32_t)(((uint64_t)rnd2 * d) >> 32)]; n3 = cur;
    d = deg[cur];
    cur = adj[(cur << 9) + (uint32_t)(((uint64_t)rnd3 * d) >> 32)]; n4 = cur;
    nvalid = 5u;
  }

  /* mean embedding over valid positions; lane == dim (PE_DIM == 64) */
  float s = embed[n0 * PE_DIM + lane];
  if (nvalid == 5u) {
    s += embed[n1 * PE_DIM + lane];
    s += embed[n2 * PE_DIM + lane];
    s += embed[n3 * PE_DIM + lane];
    s += embed[n4 * PE_DIM + lane];
  }
  const float m = s / (float)nvalid;

  atomicAdd(&pe_sum[n0 * PE_DIM + lane], m);
  if (lane == 0) atomicAdd(&cnt[n0], 1u);
  if (nvalid == 5u) {
    atomicAdd(&pe_sum[n1 * PE_DIM + lane], m);
    atomicAdd(&pe_sum[n2 * PE_DIM + lane], m);
    atomicAdd(&pe_sum[n3 * PE_DIM + lane], m);
    atomicAdd(&pe_sum[n4 * PE_DIM + lane], m);
    if (lane == 0) {
      atomicAdd(&cnt[n1], 1u);
      atomicAdd(&cnt[n2], 1u);
      atomicAdd(&cnt[n3], 1u);
      atomicAdd(&cnt[n4], 1u);
    }
  }
}

/* ---- K4: out = [x | pe_sum/cnt] in f32 ---- */
__global__ void k_out(const float* __restrict__ x,
                      const float* __restrict__ pe_sum,
                      const unsigned int* __restrict__ cnt,
                      float* __restrict__ out) {
  const int idx = blockIdx.x * 256 + threadIdx.x;
  const int i = idx / OUT_COLS;
  const int c = idx - i * OUT_COLS;
  if (c < D_X) {
    out[idx] = x[i * D_X + c];
  } else {
    const int d = c - D_X;
    const unsigned int k = cnt[i];
    out[idx] = (k > 0) ? pe_sum[i * PE_DIM + d] / (float)k : 0.f;
  }
}

extern "C" void kernel_launch(void* const* d_in, const int* in_sizes, int n_in,
                              void* d_out, int out_size, void* d_ws, size_t ws_size,
                              hipStream_t stream) {
  const float* x   = (const float*)d_in[0];
  const float* inc = (const float*)d_in[1];
  const float* emb = (const float*)d_in[2];

  char* ws = (char*)d_ws;
  ulonglong2*     masks = (ulonglong2*)(ws + OFF_MASKS);
  unsigned int*   deg   = (unsigned int*)(ws + OFF_DEG);
  unsigned short* adj   = (unsigned short*)(ws + OFF_ADJ);
  float*          pe    = (float*)(ws + OFF_PE);
  unsigned int*   cnt   = (unsigned int*)(ws + OFF_CNT);

  /* pe_sum + cnt are contiguous: zero both each call (graph-capture safe) */
  hipMemsetAsync(pe, 0, (size_t)N_NODES * PE_DIM * 4u + (size_t)N_NODES * 4u,
                 stream);

  k_masks<<<N_NODES / 4, 256, 0, stream>>>(inc, masks);
  k_adj  <<<N_NODES / 8, 512, 0, stream>>>(masks, adj, deg);
  k_walk <<<N_WALKS_TOT / 4, 256, 0, stream>>>(deg, adj, emb, pe, cnt);
  k_out  <<<OUT_TOT / 256, 256, 0, stream>>>(x, pe, cnt, (float*)d_out);
}

// Round 5
// 77.629 us; speedup vs baseline: 2.1117x; 1.2092x over previous
//
#include <hip/hip_runtime.h>
#include <hip/hip_fp16.h>
#include <stdint.h>

#define N_NODES   4096
#define N_EDGES   128
#define D_X       128
#define PE_DIM    64
#define NUM_WALKS 10
#define WALK_LEN  5
#define N_WALKS_TOT (N_NODES * NUM_WALKS)   /* 40960 */
#define OUT_COLS  (D_X + PE_DIM)            /* 192 */
#define ROW_CAP   512u                      /* adjacency row stride (u16) */
#define VCAP      512u                      /* visitor list cap (max expected ~180) */

/* workspace layout (bytes) — ~13.8 MiB */
#define OFF_MASKS   0u                                    /* 64 KiB */
#define OFF_DEG     (OFF_MASKS + N_NODES * 16u)           /* 16 KiB */
#define OFF_ADJ     (OFF_DEG + N_NODES * 4u)              /* 4 MiB */
#define OFF_WM      (OFF_ADJ + N_NODES * ROW_CAP * 2u)    /* 40960*64*2 = 5 MiB */
#define OFF_VCNT    (OFF_WM + N_WALKS_TOT * PE_DIM * 2u)  /* 16 KiB */
#define OFF_VLIST   (OFF_VCNT + N_NODES * 4u)             /* 4096*512*2 = 4 MiB */

/* ---- threefry2x32 (20 rounds) — cheap high-quality PRF ---- */
__device__ __forceinline__ void tf2x32(uint32_t kk0, uint32_t kk1,
                                       uint32_t x0, uint32_t x1,
                                       uint32_t& o0, uint32_t& o1) {
  const uint32_t kk2 = kk0 ^ kk1 ^ 0x1BD11BDAu;
  x0 += kk0; x1 += kk1;
  auto rnd = [&](int r) {
    x0 += x1;
    x1 = (x1 << r) | (x1 >> (32 - r));
    x1 ^= x0;
  };
  rnd(13); rnd(15); rnd(26); rnd(6);   x0 += kk1; x1 += kk2 + 1u;
  rnd(17); rnd(29); rnd(16); rnd(24);  x0 += kk2; x1 += kk0 + 2u;
  rnd(13); rnd(15); rnd(26); rnd(6);   x0 += kk0; x1 += kk1 + 3u;
  rnd(17); rnd(29); rnd(16); rnd(24);  x0 += kk1; x1 += kk2 + 4u;
  rnd(13); rnd(15); rnd(26); rnd(6);   x0 += kk2; x1 += kk0 + 5u;
  o0 = x0; o1 = x1;
}

/* ---- K1: 128-bit incidence masks (one wave per node) ---- */
__global__ void k_masks(const float* __restrict__ inc,
                        ulonglong2* __restrict__ masks) {
  const int wid = threadIdx.x >> 6, lane = threadIdx.x & 63;
  const int i = blockIdx.x * 4 + wid;
  const float a = inc[i * N_EDGES + lane];
  const float b = inc[i * N_EDGES + 64 + lane];
  const unsigned long long m0 = __ballot(a != 0.f);
  const unsigned long long m1 = __ballot(b != 0.f);
  if (lane == 0) masks[i] = make_ulonglong2(m0, m1);
}

/* ---- K2: adjacency rows (fixed stride) + degree, masks staged in LDS ---- */
__global__ void __launch_bounds__(512)
k_adj(const ulonglong2* __restrict__ masks,
      unsigned short* __restrict__ adj, unsigned int* __restrict__ deg) {
  __shared__ ulonglong2 sm[N_NODES];
  for (int k = threadIdx.x; k < N_NODES; k += 512) sm[k] = masks[k];
  __syncthreads();
  const int wid = threadIdx.x >> 6, lane = threadIdx.x & 63;
  const int i = blockIdx.x * 8 + wid;
  const ulonglong2 mi = sm[i];
  unsigned short* row = adj + (unsigned int)i * ROW_CAP;
  unsigned int base = 0;
  for (int g = 0; g < N_NODES / 64; ++g) {
    const int j = g * 64 + lane;
    const ulonglong2 mj = sm[j];
    const bool pred = (((mi.x & mj.x) | (mi.y & mj.y)) != 0ull) && (j != i);
    const unsigned long long bal = __ballot(pred);
    if (pred) {
      const unsigned int off =
          (unsigned int)__popcll(bal & ((1ull << lane) - 1ull));
      const unsigned int pos = base + off;
      if (pos < ROW_CAP) row[pos] = (unsigned short)j;
    }
    base += (unsigned int)__popcll(bal);
  }
  if (lane == 0) deg[i] = (base < ROW_CAP) ? base : ROW_CAP;
}

/* ---- K3: walks + mean embed; emit m (f16) + visit records ----
   Symmetric graph => walks are full-length or length-1 (deg(start)==0). */
__global__ void __launch_bounds__(256)
k_walk(const unsigned int* __restrict__ deg,
       const unsigned short* __restrict__ adj,
       const float* __restrict__ embed,
       __half* __restrict__ walk_m,
       unsigned int* __restrict__ vcnt, unsigned short* __restrict__ vlist) {
  const int wid = threadIdx.x >> 6, lane = threadIdx.x & 63;
  const int w = blockIdx.x * 4 + wid;

  /* 4 independent u32 per walk from 2 threefry blocks */
  uint32_t a0, a1;
  tf2x32(0u, 42u, (uint32_t)w, (uint32_t)(lane & 1), a0, a1);
  const uint32_t rnd0 = __shfl(a0, 0);
  const uint32_t rnd1 = __shfl(a1, 0);
  const uint32_t rnd2 = __shfl(a0, 1);
  const uint32_t rnd3 = __shfl(a1, 1);

  const uint32_t n0 = (uint32_t)w / NUM_WALKS;
  uint32_t n1, n2, n3, n4, nvalid;
  const unsigned int d0 = deg[n0];
  if (d0 == 0) {
    n1 = n2 = n3 = n4 = n0;
    nvalid = 1u;
  } else {
    uint32_t cur = n0;
    unsigned int d;
    cur = adj[(cur << 9) + (uint32_t)(((uint64_t)rnd0 * d0) >> 32)]; n1 = cur;
    d = deg[cur];
    cur = adj[(cur << 9) + (uint32_t)(((uint64_t)rnd1 * d) >> 32)]; n2 = cur;
    d = deg[cur];
    cur = adj[(cur << 9) + (uint32_t)(((uint64_t)rnd2 * d) >> 32)]; n3 = cur;
    d = deg[cur];
    cur = adj[(cur << 9) + (uint32_t)(((uint64_t)rnd3 * d) >> 32)]; n4 = cur;
    nvalid = 5u;
  }

  /* mean embedding over valid positions; lane == dim (PE_DIM == 64) */
  float s = embed[n0 * PE_DIM + lane];
  if (nvalid == 5u) {
    s += embed[n1 * PE_DIM + lane];
    s += embed[n2 * PE_DIM + lane];
    s += embed[n3 * PE_DIM + lane];
    s += embed[n4 * PE_DIM + lane];
  }
  const float m = s / (float)nvalid;

  /* coalesced f16 store of m */
  walk_m[(unsigned int)w * PE_DIM + lane] = __float2half(m);

  /* visit records: lanes 0..nvalid-1 each allocate a slot */
  if ((unsigned int)lane < nvalid) {
    uint32_t node = n0;
    if (lane == 1) node = n1;
    if (lane == 2) node = n2;
    if (lane == 3) node = n3;
    if (lane == 4) node = n4;
    const unsigned int slot = atomicAdd(&vcnt[node], 1u);
    if (slot < VCAP) vlist[node * VCAP + slot] = (unsigned short)w;
  }
}

/* ---- K4: per-node gather of visitor means -> pe columns of out ---- */
__global__ void __launch_bounds__(256)
k_gather(const __half* __restrict__ walk_m,
         const unsigned int* __restrict__ vcnt,
         const unsigned short* __restrict__ vlist,
         float* __restrict__ out) {
  const int wid = threadIdx.x >> 6, lane = threadIdx.x & 63;
  const int v = blockIdx.x * 4 + wid;
  unsigned int c = vcnt[v];
  if (c > VCAP) c = VCAP;
  const unsigned short* vl = vlist + (unsigned int)v * VCAP;
  float s = 0.f;
  unsigned int i = 0;
  for (; i + 4 <= c; i += 4) {
    const uint64_t q = *(const uint64_t*)(vl + i);
    const uint32_t w0 = (uint32_t)(q & 0xFFFFull);
    const uint32_t w1 = (uint32_t)((q >> 16) & 0xFFFFull);
    const uint32_t w2 = (uint32_t)((q >> 32) & 0xFFFFull);
    const uint32_t w3 = (uint32_t)(q >> 48);
    const float m0 = __half2float(walk_m[w0 * PE_DIM + lane]);
    const float m1 = __half2float(walk_m[w1 * PE_DIM + lane]);
    const float m2 = __half2float(walk_m[w2 * PE_DIM + lane]);
    const float m3 = __half2float(walk_m[w3 * PE_DIM + lane]);
    s += (m0 + m1) + (m2 + m3);
  }
  for (; i < c; ++i) {
    const uint32_t ww = vl[i];
    s += __half2float(walk_m[ww * PE_DIM + lane]);
  }
  out[(unsigned int)v * OUT_COLS + D_X + lane] = c ? s / (float)c : 0.f;
}

/* ---- K5: strided copy of x into out[:, :128] (float4) ---- */
__global__ void k_copyx(const float* __restrict__ x, float* __restrict__ out) {
  const int t = blockIdx.x * 256 + threadIdx.x;   /* 131072 threads */
  const int row = t >> 5, c4 = t & 31;
  const float4 v = ((const float4*)x)[(row << 5) + c4];
  ((float4*)(out + (unsigned int)row * OUT_COLS))[c4] = v;
}

extern "C" void kernel_launch(void* const* d_in, const int* in_sizes, int n_in,
                              void* d_out, int out_size, void* d_ws, size_t ws_size,
                              hipStream_t stream) {
  const float* x   = (const float*)d_in[0];
  const float* inc = (const float*)d_in[1];
  const float* emb = (const float*)d_in[2];
  float* out = (float*)d_out;

  char* ws = (char*)d_ws;
  ulonglong2*     masks = (ulonglong2*)(ws + OFF_MASKS);
  unsigned int*   deg   = (unsigned int*)(ws + OFF_DEG);
  unsigned short* adj   = (unsigned short*)(ws + OFF_ADJ);
  __half*         wm    = (__half*)(ws + OFF_WM);
  unsigned int*   vcnt  = (unsigned int*)(ws + OFF_VCNT);
  unsigned short* vlist = (unsigned short*)(ws + OFF_VLIST);

  /* only vcnt needs zeroing each call (slot allocation) */
  hipMemsetAsync(vcnt, 0, (size_t)N_NODES * 4u, stream);

  k_masks <<<N_NODES / 4, 256, 0, stream>>>(inc, masks);
  k_adj   <<<N_NODES / 8, 512, 0, stream>>>(masks, adj, deg);
  k_walk  <<<N_WALKS_TOT / 4, 256, 0, stream>>>(deg, adj, emb, wm, vcnt, vlist);
  k_gather<<<N_NODES / 4, 256, 0, stream>>>(wm, vcnt, vlist, out);
  k_copyx <<<(N_NODES * D_X / 4) / 256, 256, 0, stream>>>(x, out);
}

// Round 6
// 74.238 us; speedup vs baseline: 2.2082x; 1.0457x over previous
//
#include <hip/hip_runtime.h>
#include <hip/hip_fp16.h>
#include <stdint.h>

#define N_NODES   4096
#define N_EDGES   128
#define D_X       128
#define PE_DIM    64
#define NUM_WALKS 10
#define WALK_LEN  5
#define N_WALKS_TOT (N_NODES * NUM_WALKS)   /* 40960 */
#define OUT_COLS  (D_X + PE_DIM)            /* 192 */
#define ROW_CAP   512u                      /* adjacency row stride (u16) */
#define VCAP      512u                      /* visitor list cap (max expected ~180) */

/* workspace layout (bytes) — ~13.8 MiB */
#define OFF_MASKS   0u                                    /* 64 KiB */
#define OFF_DEG     (OFF_MASKS + N_NODES * 16u)           /* 16 KiB */
#define OFF_ADJ     (OFF_DEG + N_NODES * 4u)              /* 4 MiB */
#define OFF_WM      (OFF_ADJ + N_NODES * ROW_CAP * 2u)    /* 40960*64*2 = 5 MiB */
#define OFF_VCNT    (OFF_WM + N_WALKS_TOT * PE_DIM * 2u)  /* 16 KiB */
#define OFF_VLIST   (OFF_VCNT + N_NODES * 4u)             /* 4096*512*2 = 4 MiB */

/* ---- threefry2x32 (20 rounds) — cheap high-quality PRF ---- */
__device__ __forceinline__ void tf2x32(uint32_t kk0, uint32_t kk1,
                                       uint32_t x0, uint32_t x1,
                                       uint32_t& o0, uint32_t& o1) {
  const uint32_t kk2 = kk0 ^ kk1 ^ 0x1BD11BDAu;
  x0 += kk0; x1 += kk1;
  auto rnd = [&](int r) {
    x0 += x1;
    x1 = (x1 << r) | (x1 >> (32 - r));
    x1 ^= x0;
  };
  rnd(13); rnd(15); rnd(26); rnd(6);   x0 += kk1; x1 += kk2 + 1u;
  rnd(17); rnd(29); rnd(16); rnd(24);  x0 += kk2; x1 += kk0 + 2u;
  rnd(13); rnd(15); rnd(26); rnd(6);   x0 += kk0; x1 += kk1 + 3u;
  rnd(17); rnd(29); rnd(16); rnd(24);  x0 += kk1; x1 += kk2 + 4u;
  rnd(13); rnd(15); rnd(26); rnd(6);   x0 += kk2; x1 += kk0 + 5u;
  o0 = x0; o1 = x1;
}

/* ---- K1: 128-bit incidence masks (one wave per node) + vcnt zeroing ---- */
__global__ void k_masks(const float* __restrict__ inc,
                        ulonglong2* __restrict__ masks,
                        unsigned int* __restrict__ vcnt) {
  const int wid = threadIdx.x >> 6, lane = threadIdx.x & 63;
  const int i = blockIdx.x * 4 + wid;
  const float a = inc[i * N_EDGES + lane];
  const float b = inc[i * N_EDGES + 64 + lane];
  const unsigned long long m0 = __ballot(a != 0.f);
  const unsigned long long m1 = __ballot(b != 0.f);
  if (lane == 0) {
    masks[i] = make_ulonglong2(m0, m1);
    vcnt[i] = 0u;   /* replaces the 43us fillBufferAligned dispatch */
  }
}

/* ---- K2: adjacency rows (fixed stride) + degree, masks staged in LDS ---- */
__global__ void __launch_bounds__(512)
k_adj(const ulonglong2* __restrict__ masks,
      unsigned short* __restrict__ adj, unsigned int* __restrict__ deg) {
  __shared__ ulonglong2 sm[N_NODES];
  for (int k = threadIdx.x; k < N_NODES; k += 512) sm[k] = masks[k];
  __syncthreads();
  const int wid = threadIdx.x >> 6, lane = threadIdx.x & 63;
  const int i = blockIdx.x * 8 + wid;
  const ulonglong2 mi = sm[i];
  unsigned short* row = adj + (unsigned int)i * ROW_CAP;
  unsigned int base = 0;
  for (int g = 0; g < N_NODES / 64; ++g) {
    const int j = g * 64 + lane;
    const ulonglong2 mj = sm[j];
    const bool pred = (((mi.x & mj.x) | (mi.y & mj.y)) != 0ull) && (j != i);
    const unsigned long long bal = __ballot(pred);
    if (pred) {
      const unsigned int off =
          (unsigned int)__popcll(bal & ((1ull << lane) - 1ull));
      const unsigned int pos = base + off;
      if (pos < ROW_CAP) row[pos] = (unsigned short)j;
    }
    base += (unsigned int)__popcll(bal);
  }
  if (lane == 0) deg[i] = (base < ROW_CAP) ? base : ROW_CAP;
}

/* ---- K3: walks + mean embed; emit m (f16) + visit records ----
   Symmetric graph => walks are full-length or length-1 (deg(start)==0). */
__global__ void __launch_bounds__(256)
k_walk(const unsigned int* __restrict__ deg,
       const unsigned short* __restrict__ adj,
       const float* __restrict__ embed,
       __half* __restrict__ walk_m,
       unsigned int* __restrict__ vcnt, unsigned short* __restrict__ vlist) {
  const int wid = threadIdx.x >> 6, lane = threadIdx.x & 63;
  const int w = blockIdx.x * 4 + wid;

  /* 4 independent u32 per walk from 2 threefry blocks */
  uint32_t a0, a1;
  tf2x32(0u, 42u, (uint32_t)w, (uint32_t)(lane & 1), a0, a1);
  const uint32_t rnd0 = __shfl(a0, 0);
  const uint32_t rnd1 = __shfl(a1, 0);
  const uint32_t rnd2 = __shfl(a0, 1);
  const uint32_t rnd3 = __shfl(a1, 1);

  const uint32_t n0 = (uint32_t)w / NUM_WALKS;
  uint32_t n1, n2, n3, n4, nvalid;
  const unsigned int d0 = deg[n0];
  if (d0 == 0) {
    n1 = n2 = n3 = n4 = n0;
    nvalid = 1u;
  } else {
    uint32_t cur = n0;
    unsigned int d;
    cur = adj[(cur << 9) + (uint32_t)(((uint64_t)rnd0 * d0) >> 32)]; n1 = cur;
    d = deg[cur];
    cur = adj[(cur << 9) + (uint32_t)(((uint64_t)rnd1 * d) >> 32)]; n2 = cur;
    d = deg[cur];
    cur = adj[(cur << 9) + (uint32_t)(((uint64_t)rnd2 * d) >> 32)]; n3 = cur;
    d = deg[cur];
    cur = adj[(cur << 9) + (uint32_t)(((uint64_t)rnd3 * d) >> 32)]; n4 = cur;
    nvalid = 5u;
  }

  /* mean embedding over valid positions; lane == dim (PE_DIM == 64) */
  float s = embed[n0 * PE_DIM + lane];
  if (nvalid == 5u) {
    s += embed[n1 * PE_DIM + lane];
    s += embed[n2 * PE_DIM + lane];
    s += embed[n3 * PE_DIM + lane];
    s += embed[n4 * PE_DIM + lane];
  }
  const float m = s / (float)nvalid;

  /* coalesced f16 store of m */
  walk_m[(unsigned int)w * PE_DIM + lane] = __float2half(m);

  /* visit records: lanes 0..nvalid-1 each allocate a slot */
  if ((unsigned int)lane < nvalid) {
    uint32_t node = n0;
    if (lane == 1) node = n1;
    if (lane == 2) node = n2;
    if (lane == 3) node = n3;
    if (lane == 4) node = n4;
    const unsigned int slot = atomicAdd(&vcnt[node], 1u);
    if (slot < VCAP) vlist[node * VCAP + slot] = (unsigned short)w;
  }
}

/* ---- K4: per-node gather of visitor means -> pe cols; also copy x row ---- */
__global__ void __launch_bounds__(256)
k_gather(const __half* __restrict__ walk_m,
         const unsigned int* __restrict__ vcnt,
         const unsigned short* __restrict__ vlist,
         const float* __restrict__ x,
         float* __restrict__ out) {
  const int wid = threadIdx.x >> 6, lane = threadIdx.x & 63;
  const int v = blockIdx.x * 4 + wid;

  /* x passthrough: 128 floats = 64 lanes x float2 */
  const float2 xv = ((const float2*)(x + (unsigned int)v * D_X))[lane];
  ((float2*)(out + (unsigned int)v * OUT_COLS))[lane] = xv;

  unsigned int c = vcnt[v];
  if (c > VCAP) c = VCAP;
  const unsigned short* vl = vlist + (unsigned int)v * VCAP;
  float s = 0.f;
  unsigned int i = 0;
  for (; i + 4 <= c; i += 4) {
    const uint64_t q = *(const uint64_t*)(vl + i);
    const uint32_t w0 = (uint32_t)(q & 0xFFFFull);
    const uint32_t w1 = (uint32_t)((q >> 16) & 0xFFFFull);
    const uint32_t w2 = (uint32_t)((q >> 32) & 0xFFFFull);
    const uint32_t w3 = (uint32_t)(q >> 48);
    const float m0 = __half2float(walk_m[w0 * PE_DIM + lane]);
    const float m1 = __half2float(walk_m[w1 * PE_DIM + lane]);
    const float m2 = __half2float(walk_m[w2 * PE_DIM + lane]);
    const float m3 = __half2float(walk_m[w3 * PE_DIM + lane]);
    s += (m0 + m1) + (m2 + m3);
  }
  for (; i < c; ++i) {
    const uint32_t ww = vl[i];
    s += __half2float(walk_m[ww * PE_DIM + lane]);
  }
  out[(unsigned int)v * OUT_COLS + D_X + lane] = c ? s / (float)c : 0.f;
}

extern "C" void kernel_launch(void* const* d_in, const int* in_sizes, int n_in,
                              void* d_out, int out_size, void* d_ws, size_t ws_size,
                              hipStream_t stream) {
  const float* x   = (const float*)d_in[0];
  const float* inc = (const float*)d_in[1];
  const float* emb = (const float*)d_in[2];
  float* out = (float*)d_out;

  char* ws = (char*)d_ws;
  ulonglong2*     masks = (ulonglong2*)(ws + OFF_MASKS);
  unsigned int*   deg   = (unsigned int*)(ws + OFF_DEG);
  unsigned short* adj   = (unsigned short*)(ws + OFF_ADJ);
  __half*         wm    = (__half*)(ws + OFF_WM);
  unsigned int*   vcnt  = (unsigned int*)(ws + OFF_VCNT);
  unsigned short* vlist = (unsigned short*)(ws + OFF_VLIST);

  k_masks <<<N_NODES / 4, 256, 0, stream>>>(inc, masks, vcnt);
  k_adj   <<<N_NODES / 8, 512, 0, stream>>>(masks, adj, deg);
  k_walk  <<<N_WALKS_TOT / 4, 256, 0, stream>>>(deg, adj, emb, wm, vcnt, vlist);
  k_gather<<<N_NODES / 4, 256, 0, stream>>>(wm, vcnt, vlist, x, out);
}

// Round 7
// 62.291 us; speedup vs baseline: 2.6317x; 1.1918x over previous
//
#include <hip/hip_runtime.h>
#include <hip/hip_fp16.h>
#include <stdint.h>

#define N_NODES   4096
#define N_EDGES   128
#define D_X       128
#define PE_DIM    64
#define NUM_WALKS 10
#define WALK_LEN  5
#define N_WALKS_TOT (N_NODES * NUM_WALKS)   /* 40960 */
#define OUT_COLS  (D_X + PE_DIM)            /* 192 */
#define ROW_CAP   512u                      /* adjacency row stride (u16) */
#define VCAP      512u                      /* visitor list cap (max expected ~180) */

/* workspace layout (bytes) — ~13.8 MiB */
#define OFF_MASKS   0u                                    /* 64 KiB */
#define OFF_DEG     (OFF_MASKS + N_NODES * 16u)           /* 16 KiB */
#define OFF_ADJ     (OFF_DEG + N_NODES * 4u)              /* 4 MiB */
#define OFF_WM      (OFF_ADJ + N_NODES * ROW_CAP * 2u)    /* 40960*64*2 = 5 MiB */
#define OFF_VCNT    (OFF_WM + N_WALKS_TOT * PE_DIM * 2u)  /* 16 KiB */
#define OFF_VLIST   (OFF_VCNT + N_NODES * 4u)             /* 4096*512*2 = 4 MiB */

/* ---- threefry2x32 (20 rounds) — cheap high-quality PRF ---- */
__device__ __forceinline__ void tf2x32(uint32_t kk0, uint32_t kk1,
                                       uint32_t x0, uint32_t x1,
                                       uint32_t& o0, uint32_t& o1) {
  const uint32_t kk2 = kk0 ^ kk1 ^ 0x1BD11BDAu;
  x0 += kk0; x1 += kk1;
  auto rnd = [&](int r) {
    x0 += x1;
    x1 = (x1 << r) | (x1 >> (32 - r));
    x1 ^= x0;
  };
  rnd(13); rnd(15); rnd(26); rnd(6);   x0 += kk1; x1 += kk2 + 1u;
  rnd(17); rnd(29); rnd(16); rnd(24);  x0 += kk2; x1 += kk0 + 2u;
  rnd(13); rnd(15); rnd(26); rnd(6);   x0 += kk0; x1 += kk1 + 3u;
  rnd(17); rnd(29); rnd(16); rnd(24);  x0 += kk1; x1 += kk2 + 4u;
  rnd(13); rnd(15); rnd(26); rnd(6);   x0 += kk2; x1 += kk0 + 5u;
  o0 = x0; o1 = x1;
}

/* ---- K1: 128-bit incidence masks (one wave per node) + vcnt zeroing ---- */
__global__ void k_masks(const float* __restrict__ inc,
                        ulonglong2* __restrict__ masks,
                        unsigned int* __restrict__ vcnt) {
  const int wid = threadIdx.x >> 6, lane = threadIdx.x & 63;
  const int i = blockIdx.x * 4 + wid;
  const float a = inc[i * N_EDGES + lane];
  const float b = inc[i * N_EDGES + 64 + lane];
  const unsigned long long m0 = __ballot(a != 0.f);
  const unsigned long long m1 = __ballot(b != 0.f);
  if (lane == 0) {
    masks[i] = make_ulonglong2(m0, m1);
    vcnt[i] = 0u;
  }
}

/* ---- K2: adjacency rows (fixed stride) + degree, masks staged in LDS ---- */
__global__ void __launch_bounds__(512)
k_adj(const ulonglong2* __restrict__ masks,
      unsigned short* __restrict__ adj, unsigned int* __restrict__ deg) {
  __shared__ ulonglong2 sm[N_NODES];
  for (int k = threadIdx.x; k < N_NODES; k += 512) sm[k] = masks[k];
  __syncthreads();
  const int wid = threadIdx.x >> 6, lane = threadIdx.x & 63;
  const int i = blockIdx.x * 8 + wid;
  const ulonglong2 mi = sm[i];
  unsigned short* row = adj + (unsigned int)i * ROW_CAP;
  unsigned int base = 0;
  for (int g = 0; g < N_NODES / 64; ++g) {
    const int j = g * 64 + lane;
    const ulonglong2 mj = sm[j];
    const bool pred = (((mi.x & mj.x) | (mi.y & mj.y)) != 0ull) && (j != i);
    const unsigned long long bal = __ballot(pred);
    if (pred) {
      const unsigned int off =
          (unsigned int)__popcll(bal & ((1ull << lane) - 1ull));
      const unsigned int pos = base + off;
      if (pos < ROW_CAP) row[pos] = (unsigned short)j;
    }
    base += (unsigned int)__popcll(bal);
  }
  if (lane == 0) deg[i] = (base < ROW_CAP) ? base : ROW_CAP;
}

/* ---- K3: walks + mean embed; emit m (f16) + visit records ----
   Symmetric graph => walks are full-length or length-1 (deg(start)==0). */
__global__ void __launch_bounds__(256)
k_walk(const unsigned int* __restrict__ deg,
       const unsigned short* __restrict__ adj,
       const float* __restrict__ embed,
       __half* __restrict__ walk_m,
       unsigned int* __restrict__ vcnt, unsigned short* __restrict__ vlist) {
  const int wid = threadIdx.x >> 6, lane = threadIdx.x & 63;
  const int w = blockIdx.x * 4 + wid;

  /* 4 independent u32 per walk from 2 threefry blocks */
  uint32_t a0, a1;
  tf2x32(0u, 42u, (uint32_t)w, (uint32_t)(lane & 1), a0, a1);
  const uint32_t rnd0 = __shfl(a0, 0);
  const uint32_t rnd1 = __shfl(a1, 0);
  const uint32_t rnd2 = __shfl(a0, 1);
  const uint32_t rnd3 = __shfl(a1, 1);

  const uint32_t n0 = (uint32_t)w / NUM_WALKS;
  uint32_t n1, n2, n3, n4, nvalid;
  const unsigned int d0 = deg[n0];
  if (d0 == 0) {
    n1 = n2 = n3 = n4 = n0;
    nvalid = 1u;
  } else {
    uint32_t cur = n0;
    unsigned int d;
    cur = adj[(cur << 9) + (uint32_t)(((uint64_t)rnd0 * d0) >> 32)]; n1 = cur;
    d = deg[cur];
    cur = adj[(cur << 9) + (uint32_t)(((uint64_t)rnd1 * d) >> 32)]; n2 = cur;
    d = deg[cur];
    cur = adj[(cur << 9) + (uint32_t)(((uint64_t)rnd2 * d) >> 32)]; n3 = cur;
    d = deg[cur];
    cur = adj[(cur << 9) + (uint32_t)(((uint64_t)rnd3 * d) >> 32)]; n4 = cur;
    nvalid = 5u;
  }

  /* mean embedding over valid positions; lane == dim (PE_DIM == 64) */
  float s = embed[n0 * PE_DIM + lane];
  if (nvalid == 5u) {
    s += embed[n1 * PE_DIM + lane];
    s += embed[n2 * PE_DIM + lane];
    s += embed[n3 * PE_DIM + lane];
    s += embed[n4 * PE_DIM + lane];
  }
  const float m = s / (float)nvalid;

  /* coalesced f16 store of m */
  walk_m[(unsigned int)w * PE_DIM + lane] = __float2half(m);

  /* visit records: lanes 0..nvalid-1 each allocate a slot */
  if ((unsigned int)lane < nvalid) {
    uint32_t node = n0;
    if (lane == 1) node = n1;
    if (lane == 2) node = n2;
    if (lane == 3) node = n3;
    if (lane == 4) node = n4;
    const unsigned int slot = atomicAdd(&vcnt[node], 1u);
    if (slot < VCAP) vlist[node * VCAP + slot] = (unsigned short)w;
  }
}

/* ---- K4: one block per node; 4 waves x 8-deep ILP gather of visitor means.
   Kills the serial straggler tail (c up to ~180 visitors on hub nodes). ---- */
__global__ void __launch_bounds__(256)
k_gather(const __half* __restrict__ walk_m,
         const unsigned int* __restrict__ vcnt,
         const unsigned short* __restrict__ vlist,
         const float* __restrict__ x,
         float* __restrict__ out) {
  __shared__ float red[4][PE_DIM];
  const int wid = threadIdx.x >> 6, lane = threadIdx.x & 63;
  const int v = blockIdx.x;

  /* x passthrough by wave 1 (independent of the reduction) */
  if (wid == 1) {
    const float2 xv = ((const float2*)(x + (unsigned int)v * D_X))[lane];
    ((float2*)(out + (unsigned int)v * OUT_COLS))[lane] = xv;
  }

  unsigned int c = vcnt[v];
  if (c > VCAP) c = VCAP;
  const unsigned short* vl = vlist + (unsigned int)v * VCAP;

  float s = 0.f;
  for (unsigned int base = (unsigned int)wid * 8u; base < c; base += 32u) {
#pragma unroll
    for (int q = 0; q < 8; ++q) {
      const unsigned int idx = base + (unsigned int)q;
      const bool ok = idx < c;
      const unsigned int ww = ok ? (unsigned int)vl[idx] : (unsigned int)vl[0];
      const float val = __half2float(walk_m[ww * PE_DIM + lane]);
      s += ok ? val : 0.f;
    }
  }
  red[wid][lane] = s;
  __syncthreads();
  if (wid == 0) {
    const float t = red[0][lane] + red[1][lane] + red[2][lane] + red[3][lane];
    out[(unsigned int)v * OUT_COLS + D_X + lane] = c ? t / (float)c : 0.f;
  }
}

extern "C" void kernel_launch(void* const* d_in, const int* in_sizes, int n_in,
                              void* d_out, int out_size, void* d_ws, size_t ws_size,
                              hipStream_t stream) {
  const float* x   = (const float*)d_in[0];
  const float* inc = (const float*)d_in[1];
  const float* emb = (const float*)d_in[2];
  float* out = (float*)d_out;

  char* ws = (char*)d_ws;
  ulonglong2*     masks = (ulonglong2*)(ws + OFF_MASKS);
  unsigned int*   deg   = (unsigned int*)(ws + OFF_DEG);
  unsigned short* adj   = (unsigned short*)(ws + OFF_ADJ);
  __half*         wm    = (__half*)(ws + OFF_WM);
  unsigned int*   vcnt  = (unsigned int*)(ws + OFF_VCNT);
  unsigned short* vlist = (unsigned short*)(ws + OFF_VLIST);

  k_masks <<<N_NODES / 4, 256, 0, stream>>>(inc, masks, vcnt);
  k_adj   <<<N_NODES / 8, 512, 0, stream>>>(masks, adj, deg);
  k_walk  <<<N_WALKS_TOT / 4, 256, 0, stream>>>(deg, adj, emb, wm, vcnt, vlist);
  k_gather<<<N_NODES, 256, 0, stream>>>(wm, vcnt, vlist, x, out);
}